// Round 3
// baseline (904.619 us; speedup 1.0000x reference)
//
#include <hip/hip_runtime.h>
#include <hip/hip_bf16.h>
#include <cstdint>
#include <cstddef>

// ---------------------------------------------------------------------------
// EfficientEquilibriumLayer: LN1 -> QKV(elu+1 on Q,K) -> chunked causal linear
// attention -> O-proj + residual -> LN2 -> GELU FFN + residual.
// B=4, N=4096, D=1024, F=64. All GEMMs bf16 MFMA (16x16x32), fp32 accum.
// R1: XOR-swizzled LDS (bank conflicts 2.5e7 -> 0), tanh-GELU epilogue.
// R2: FFN as N-strips over full M (FFN2 512 -> 1024 blocks: was 2 blocks/CU,
//     grid-starved at MfmaUtil 23%); KV_A stored bf16 (saves ~67MB traffic).
// ---------------------------------------------------------------------------

typedef __attribute__((ext_vector_type(8))) short short8;
typedef __attribute__((ext_vector_type(4))) short short4v;
typedef __attribute__((ext_vector_type(4))) float floatx4;
typedef __attribute__((ext_vector_type(4))) unsigned short ushort4v;

#define DEV static __device__ __forceinline__

DEV float b2f(unsigned short u) {
    union { unsigned int i; float f; } v; v.i = ((unsigned int)u) << 16; return v.f;
}
DEV unsigned short f2b(float f) {
    union { float f; unsigned int i; } v; v.f = f;
    unsigned int i = v.i;
    unsigned int r = (i + 0x7FFFu + ((i >> 16) & 1u)) >> 16;
    return (unsigned short)r;
}

DEV void gl_lds16(const void* g, void* l) {
    __builtin_amdgcn_global_load_lds((const __attribute__((address_space(1))) void*)g,
                                     (__attribute__((address_space(3))) void*)l, 16, 0, 0);
}

// ---------------------------------------------------------------------------
// Weight prep: fp32 -> bf16, concat q/k/v weights into Wqkv [1152,1024],
// concat biases into bqkv [1152].
// ---------------------------------------------------------------------------
__global__ void eel_prep(const float* __restrict__ qw, const float* __restrict__ kw,
                         const float* __restrict__ vw, const float* __restrict__ ow,
                         const float* __restrict__ f1w, const float* __restrict__ f2w,
                         const float* __restrict__ qb, const float* __restrict__ kb,
                         const float* __restrict__ vb,
                         uint16_t* __restrict__ Wqkv, uint16_t* __restrict__ Wo,
                         uint16_t* __restrict__ W1, uint16_t* __restrict__ W2,
                         float* __restrict__ bqkv)
{
    size_t i = (size_t)blockIdx.x * 256 + threadIdx.x;
    size_t stride = (size_t)gridDim.x * 256;
    for (size_t t = i; t < 1152u * 1024u; t += stride) {
        int r = (int)(t >> 10);
        float v = (r < 64) ? qw[t] : (r < 128) ? kw[t - 65536] : vw[t - 131072];
        Wqkv[t] = f2b(v);
    }
    for (size_t t = i; t < 1048576u; t += stride) Wo[t] = f2b(ow[t]);
    for (size_t t = i; t < 4194304u; t += stride) { W1[t] = f2b(f1w[t]); W2[t] = f2b(f2w[t]); }
    if (i < 1152) bqkv[i] = (i < 64) ? qb[i] : (i < 128) ? kb[i - 64] : vb[i - 128];
}

// ---------------------------------------------------------------------------
// LayerNorm: one block per row (D=1024), fp32 in -> bf16 out.
// ---------------------------------------------------------------------------
__global__ __launch_bounds__(256) void eel_ln(const float* __restrict__ x,
                                              const float* __restrict__ w,
                                              const float* __restrict__ b,
                                              uint16_t* __restrict__ out)
{
    int row = blockIdx.x, tid = threadIdx.x;
    float4 xv = ((const float4*)(x + (size_t)row * 1024))[tid];
    float s  = xv.x + xv.y + xv.z + xv.w;
    float s2 = xv.x*xv.x + xv.y*xv.y + xv.z*xv.z + xv.w*xv.w;
#pragma unroll
    for (int off = 32; off > 0; off >>= 1) {
        s  += __shfl_down(s, off);
        s2 += __shfl_down(s2, off);
    }
    __shared__ float ps[8];
    int wv = tid >> 6;
    if ((tid & 63) == 0) { ps[wv] = s; ps[4 + wv] = s2; }
    __syncthreads();
    float mu  = (ps[0] + ps[1] + ps[2] + ps[3]) * (1.0f / 1024.0f);
    float var = (ps[4] + ps[5] + ps[6] + ps[7]) * (1.0f / 1024.0f) - mu * mu;
    float rs = rsqrtf(var + 1e-5f);
    float4 wv4 = ((const float4*)w)[tid];
    float4 bv4 = ((const float4*)b)[tid];
    ushort4v o;
    o.x = f2b((xv.x - mu) * rs * wv4.x + bv4.x);
    o.y = f2b((xv.y - mu) * rs * wv4.y + bv4.y);
    o.z = f2b((xv.z - mu) * rs * wv4.z + bv4.z);
    o.w = f2b((xv.w - mu) * rs * wv4.w + bv4.w);
    *(ushort4v*)(out + (size_t)row * 1024 + tid * 4) = o;
}

// ---------------------------------------------------------------------------
// GEMM: C[M,N] = A[M,K] @ B[N,K]^T (+epilogue). bf16 inputs, fp32 accum.
// 128x128 tile, BK=64, 4 waves, 16x16x32 MFMA, global_load_lds staging,
// XOR-swizzled LDS k-segments (conflict-free ds_read_b128).
// mode 0: out bf16 = acc+bias, cols<128 get elu(x)+1         (QKV proj)
// mode 1: out fp32 = acc+[bias]+res                          (O-proj / FFN2)
// mode 2: out bf16 = gelu_tanh(acc+bias)                     (FFN1)
// bias may be nullptr (treated as 0).
// ---------------------------------------------------------------------------
#define BM 128
#define BN 128
#define BKK 64

__global__ __launch_bounds__(256, 2) void eel_gemm(
    const uint16_t* __restrict__ A, int lda,
    const uint16_t* __restrict__ Bm, int ldb,
    int K,
    const float* __restrict__ bias,
    const float* __restrict__ res,
    uint16_t* __restrict__ outb,
    float* __restrict__ outf,
    int ldc, int mode)
{
    __shared__ uint16_t As[BM * BKK];
    __shared__ uint16_t Bs[BN * BKK];
    int tid = threadIdx.x;
    int lane = tid & 63, w = tid >> 6;
    int m0 = blockIdx.x * BM, n0 = blockIdx.y * BN;
    int wr = (w >> 1) * 64, wc = (w & 1) * 64;
    int quad = lane >> 4, l16 = lane & 15;
    floatx4 acc[4][4] = {};

    int nkb = K / BKK;
    for (int kb = 0; kb < nkb; ++kb) {
        int k0 = kb * BKK;
#pragma unroll
        for (int it = 0; it < 4; ++it) {
            int seg = it * 256 + tid;
            int row = seg >> 3, sub = seg & 7;
            int gs = sub ^ (row & 7);   // source k-segment for swizzled slot
            gl_lds16(A + (size_t)(m0 + row) * lda + k0 + gs * 8, (char*)As + seg * 16);
            gl_lds16(Bm + (size_t)(n0 + row) * ldb + k0 + gs * 8, (char*)Bs + seg * 16);
        }
        __syncthreads();
#pragma unroll
        for (int ks = 0; ks < 2; ++ks) {
            short8 a[4], b[4];
#pragma unroll
            for (int i = 0; i < 4; i++) {
                int mrow = wr + i * 16 + l16;
                int sa = (ks * 4 + quad) ^ (mrow & 7);
                a[i] = *(const short8*)((const char*)As + mrow * (BKK * 2) + sa * 16);
                int nrow = wc + i * 16 + l16;
                int sb = (ks * 4 + quad) ^ (nrow & 7);
                b[i] = *(const short8*)((const char*)Bs + nrow * (BKK * 2) + sb * 16);
            }
#pragma unroll
            for (int i = 0; i < 4; i++)
#pragma unroll
                for (int j = 0; j < 4; j++)
                    acc[i][j] = __builtin_amdgcn_mfma_f32_16x16x32_bf16(a[i], b[j], acc[i][j], 0, 0, 0);
        }
        __syncthreads();
    }

#pragma unroll
    for (int j = 0; j < 4; j++) {
        int col = n0 + wc + j * 16 + l16;
        float bv = bias ? bias[col] : 0.0f;
#pragma unroll
        for (int i = 0; i < 4; i++) {
#pragma unroll
            for (int r = 0; r < 4; r++) {
                int row = m0 + wr + i * 16 + quad * 4 + r;
                float v = acc[i][j][r] + bv;
                size_t off = (size_t)row * ldc + col;
                if (mode == 0) {
                    if (col < 128) v = (v > 0.f) ? v + 1.f : __expf(v);
                    outb[off] = f2b(v);
                } else if (mode == 1) {
                    outf[off] = v + res[off];
                } else {
                    // gelu tanh-approx; tanh(u) = 1 - 2/(exp(2u)+1), inf-safe
                    float u = 0.7978845608028654f * v * (1.0f + 0.044715f * v * v);
                    float e = __expf(2.0f * u);
                    float t = 1.0f - 2.0f / (e + 1.0f);
                    v = 0.5f * v * (1.0f + t);
                    outb[off] = f2b(v);
                }
            }
        }
    }
}

// ---------------------------------------------------------------------------
// Attention phase A1: per chunk (64 tokens) compute S = causal(Q K^T) (bf16),
// den_intra[n] = rowsum(S), Ks_c[f] = colsum(K). One block per chunk.
// QKV layout: [16384][1152] bf16, Q at col 0, K at 64, V at 128.
// ---------------------------------------------------------------------------
__global__ __launch_bounds__(256) void eel_attn_s(
    const uint16_t* __restrict__ QKV,
    uint16_t* __restrict__ Sg,      // [16384][64]
    float* __restrict__ den,        // [16384]
    float* __restrict__ KsA)        // [256][64]
{
    int chunk = blockIdx.x, tid = threadIdx.x;
    int tok0 = chunk * 64;
    __shared__ uint16_t Q[64 * 64];
    __shared__ uint16_t Kc[64 * 64];
    __shared__ float denp[64][4];
    {
        int nloc = tid >> 2, seg = tid & 3;
        const uint16_t* src = QKV + (size_t)(tok0 + nloc) * 1152 + seg * 16;
        *(short8*)(Q + nloc * 64 + seg * 16)     = *(const short8*)(src);
        *(short8*)(Q + nloc * 64 + seg * 16 + 8) = *(const short8*)(src + 8);
        src += 64;
        *(short8*)(Kc + nloc * 64 + seg * 16)     = *(const short8*)(src);
        *(short8*)(Kc + nloc * 64 + seg * 16 + 8) = *(const short8*)(src + 8);
    }
    __syncthreads();
    if (tid < 64) {
        float s = 0.f;
        for (int m = 0; m < 64; m++) s += b2f(Kc[m * 64 + tid]);
        KsA[chunk * 64 + tid] = s;
    }
    int n = tid >> 2, mg = tid & 3;
    float dsum = 0.f;
    for (int mi = 0; mi < 16; mi++) {
        int m = mg * 16 + mi;
        size_t soff = (size_t)(tok0 + n) * 64 + m;
        if (m <= n) {
            float s = 0.f;
#pragma unroll
            for (int f = 0; f < 64; f += 8) {
                short8 q8 = *(const short8*)(Q + n * 64 + f);
                short8 k8 = *(const short8*)(Kc + m * 64 + f);
#pragma unroll
                for (int j = 0; j < 8; j++)
                    s += b2f((unsigned short)q8[j]) * b2f((unsigned short)k8[j]);
            }
            dsum += s;
            Sg[soff] = f2b(s);
        } else {
            Sg[soff] = 0;
        }
    }
    denp[n][mg] = dsum;
    __syncthreads();
    if (tid < 64)
        den[tok0 + tid] = denp[tid][0] + denp[tid][1] + denp[tid][2] + denp[tid][3];
}

// ---------------------------------------------------------------------------
// Attention phase A2: per (chunk, d-panel of 128) compute KV_c[f, d] = K^T V.
// Output bf16 [256 chunks][64 f][1024 d].
// ---------------------------------------------------------------------------
__global__ __launch_bounds__(256) void eel_attn_kv(
    const uint16_t* __restrict__ QKV,
    uint16_t* __restrict__ KV_A)
{
    int bi = blockIdx.x;
    int chunk = bi >> 3, p = bi & 7;
    int tid = threadIdx.x;
    int tok0 = chunk * 64;
    __shared__ uint16_t Kc[64 * 64];
    __shared__ uint16_t Vp[64 * 128];
    {
        int r = tid >> 2, sg = tid & 3;
        const uint16_t* src = QKV + (size_t)(tok0 + r) * 1152 + 64 + sg * 16;
        *(short8*)(Kc + r * 64 + sg * 16)     = *(const short8*)(src);
        *(short8*)(Kc + r * 64 + sg * 16 + 8) = *(const short8*)(src + 8);
    }
#pragma unroll
    for (int it = 0; it < 2; it++) {
        int s = it * 256 + tid;
        int r = s >> 3, sub = s & 7;
        const uint16_t* src = QKV + (size_t)(tok0 + r) * 1152 + 128 + p * 128 + sub * 16;
        *(short8*)(Vp + r * 128 + sub * 16)     = *(const short8*)(src);
        *(short8*)(Vp + r * 128 + sub * 16 + 8) = *(const short8*)(src + 8);
    }
    __syncthreads();
    int f0 = (tid >> 5) * 8, d0 = (tid & 31) * 4;
    float acc[8][4] = {};
#pragma unroll 2
    for (int m = 0; m < 64; m++) {
        short8 k8 = *(const short8*)(Kc + m * 64 + f0);
        short4v v4 = *(const short4v*)(Vp + m * 128 + d0);
        float v0 = b2f((unsigned short)v4[0]), v1 = b2f((unsigned short)v4[1]);
        float v2 = b2f((unsigned short)v4[2]), v3 = b2f((unsigned short)v4[3]);
#pragma unroll
        for (int i = 0; i < 8; i++) {
            float kk = b2f((unsigned short)k8[i]);
            acc[i][0] += kk * v0; acc[i][1] += kk * v1;
            acc[i][2] += kk * v2; acc[i][3] += kk * v3;
        }
    }
#pragma unroll
    for (int i = 0; i < 8; i++) {
        ushort4v st;
        st.x = f2b(acc[i][0]); st.y = f2b(acc[i][1]);
        st.z = f2b(acc[i][2]); st.w = f2b(acc[i][3]);
        *(ushort4v*)(KV_A + ((size_t)chunk * 64 + f0 + i) * 1024 + p * 128 + d0) = st;
    }
}

// ---------------------------------------------------------------------------
// Phase B1: exclusive prefix over 64 chunks per batch of KV states (bf16 in,
// fp32 accum, bf16 out). Grid: 1024 blocks (b*256 + f*4 + dseg), 256 threads.
// ---------------------------------------------------------------------------
__global__ __launch_bounds__(256) void eel_kv_prefix(
    const uint16_t* __restrict__ KV_A, uint16_t* __restrict__ KV_P)
{
    int bi = blockIdx.x;
    int b = bi >> 8, rem = bi & 255;
    int f = rem >> 2;
    int d = (rem & 3) * 256 + threadIdx.x;
    float acc = 0.f;
    for (int cc = 0; cc < 64; cc++) {
        size_t idx = (((size_t)(b * 64 + cc)) * 64 + f) * 1024 + d;
        KV_P[idx] = f2b(acc);
        acc += b2f(KV_A[idx]);
    }
}

// Phase B2: exclusive prefix of Ks over chunks. Grid 4 x 64 threads.
__global__ void eel_ks_prefix(const float* __restrict__ KsA, float* __restrict__ KsP)
{
    int b = blockIdx.x, f = threadIdx.x;
    float acc = 0.f;
    for (int cc = 0; cc < 64; cc++) {
        int idx = (b * 64 + cc) * 64 + f;
        KsP[idx] = acc;
        acc += KsA[idx];
    }
}

// ---------------------------------------------------------------------------
// Phase C: per (chunk, d-panel) attn[n,d] = (Q·KV_prev + S·V) / den_full.
// ---------------------------------------------------------------------------
__global__ __launch_bounds__(256) void eel_attn_out(
    const uint16_t* __restrict__ QKV,
    const uint16_t* __restrict__ Sg,
    const float* __restrict__ den,
    const float* __restrict__ KsP,
    const uint16_t* __restrict__ KV_P,
    uint16_t* __restrict__ attn)    // [16384][1024] bf16
{
    int bi = blockIdx.x;
    int chunk = bi >> 3, p = bi & 7;
    int tid = threadIdx.x;
    int tok0 = chunk * 64;
    __shared__ uint16_t Qt[64 * 64];    // [f][n]
    __shared__ uint16_t St[64 * 64];    // [m][n]
    __shared__ uint16_t Vp[64 * 128];   // [m][d]
    __shared__ uint16_t KVp[64 * 128];  // [f][d]
    __shared__ float dfull[64];
    {
        int n = tid >> 2, fs = (tid & 3) * 16;
        const uint16_t* qsrc = QKV + (size_t)(tok0 + n) * 1152 + fs;
        short8 a0 = *(const short8*)(qsrc);
        short8 a1 = *(const short8*)(qsrc + 8);
        const uint16_t* ssrc = Sg + (size_t)(tok0 + n) * 64 + fs;
        short8 s0 = *(const short8*)(ssrc);
        short8 s1 = *(const short8*)(ssrc + 8);
#pragma unroll
        for (int j = 0; j < 8; j++) {
            Qt[(fs + j) * 64 + n]     = (unsigned short)a0[j];
            Qt[(fs + 8 + j) * 64 + n] = (unsigned short)a1[j];
            St[(fs + j) * 64 + n]     = (unsigned short)s0[j];
            St[(fs + 8 + j) * 64 + n] = (unsigned short)s1[j];
        }
    }
#pragma unroll
    for (int it = 0; it < 2; it++) {
        int s = it * 256 + tid;
        int r = s >> 3, sub = s & 7;
        const uint16_t* vsrc = QKV + (size_t)(tok0 + r) * 1152 + 128 + p * 128 + sub * 16;
        *(short8*)(Vp + r * 128 + sub * 16)     = *(const short8*)(vsrc);
        *(short8*)(Vp + r * 128 + sub * 16 + 8) = *(const short8*)(vsrc + 8);
        const uint16_t* kvsrc = KV_P + ((size_t)(chunk * 64 + r)) * 1024 + p * 128 + sub * 16;
        *(short8*)(KVp + r * 128 + sub * 16)     = *(const short8*)(kvsrc);
        *(short8*)(KVp + r * 128 + sub * 16 + 8) = *(const short8*)(kvsrc + 8);
    }
    __syncthreads();
    if (tid < 64) {
        float s = 0.f;
        for (int f = 0; f < 64; f++)
            s += b2f(Qt[f * 64 + tid]) * KsP[chunk * 64 + f];
        dfull[tid] = s + den[tok0 + tid] + 1e-6f;
    }
    __syncthreads();
    int n0 = (tid >> 5) * 8, d0 = (tid & 31) * 4;
    float acc[8][4] = {};
#pragma unroll 2
    for (int f = 0; f < 64; f++) {
        short8 q8 = *(const short8*)(Qt + f * 64 + n0);
        short4v kv4 = *(const short4v*)(KVp + f * 128 + d0);
        float v0 = b2f((unsigned short)kv4[0]), v1 = b2f((unsigned short)kv4[1]);
        float v2 = b2f((unsigned short)kv4[2]), v3 = b2f((unsigned short)kv4[3]);
#pragma unroll
        for (int i = 0; i < 8; i++) {
            float q = b2f((unsigned short)q8[i]);
            acc[i][0] += q * v0; acc[i][1] += q * v1;
            acc[i][2] += q * v2; acc[i][3] += q * v3;
        }
    }
#pragma unroll 2
    for (int m = 0; m < 64; m++) {
        short8 s8 = *(const short8*)(St + m * 64 + n0);
        short4v v4 = *(const short4v*)(Vp + m * 128 + d0);
        float v0 = b2f((unsigned short)v4[0]), v1 = b2f((unsigned short)v4[1]);
        float v2 = b2f((unsigned short)v4[2]), v3 = b2f((unsigned short)v4[3]);
#pragma unroll
        for (int i = 0; i < 8; i++) {
            float q = b2f((unsigned short)s8[i]);
            acc[i][0] += q * v0; acc[i][1] += q * v1;
            acc[i][2] += q * v2; acc[i][3] += q * v3;
        }
    }
#pragma unroll
    for (int i = 0; i < 8; i++) {
        int n = n0 + i;
        float rinv = 1.0f / dfull[n];
        ushort4v st;
        st.x = f2b(acc[i][0] * rinv);
        st.y = f2b(acc[i][1] * rinv);
        st.z = f2b(acc[i][2] * rinv);
        st.w = f2b(acc[i][3] * rinv);
        *(ushort4v*)(attn + (size_t)(tok0 + n) * 1024 + p * 128 + d0) = st;
    }
}

// ---------------------------------------------------------------------------
// Host launcher
// ---------------------------------------------------------------------------
extern "C" void kernel_launch(void* const* d_in, const int* in_sizes, int n_in,
                              void* d_out, int out_size, void* d_ws, size_t ws_size,
                              hipStream_t stream)
{
    (void)in_sizes; (void)n_in; (void)out_size; (void)ws_size;
    const float* x     = (const float*)d_in[0];
    const float* ln1w  = (const float*)d_in[1];
    const float* ln1b  = (const float*)d_in[2];
    const float* qw    = (const float*)d_in[3];
    const float* qb    = (const float*)d_in[4];
    const float* kw    = (const float*)d_in[5];
    const float* kb    = (const float*)d_in[6];
    const float* vw    = (const float*)d_in[7];
    const float* vb    = (const float*)d_in[8];
    const float* ow    = (const float*)d_in[9];
    const float* ob    = (const float*)d_in[10];
    const float* ln2w  = (const float*)d_in[11];
    const float* ln2b  = (const float*)d_in[12];
    const float* f1w   = (const float*)d_in[13];
    const float* f1b   = (const float*)d_in[14];
    const float* f2w   = (const float*)d_in[15];
    const float* f2bs  = (const float*)d_in[16];
    float* out = (float*)d_out;
    char* ws = (char*)d_ws;

    // workspace layout (bytes)
    const size_t o_Wqkv = 0;                              // 1152*1024*2
    const size_t o_Wo   = o_Wqkv + 2359296;               // 1024*1024*2
    const size_t o_W1   = o_Wo   + 2097152;               // 4096*1024*2
    const size_t o_W2   = o_W1   + 8388608;               // 1024*4096*2
    const size_t o_bqkv = o_W2   + 8388608;               // 1152*4
    const size_t O_XN   = 21238272;   // x_norm bf16 33554432 (later: attn)
    const size_t O_QKV  = 54792704;   // QKV bf16 37748736    (later: h_norm)
    const size_t O_S    = 92541440;   // S bf16 2097152
    const size_t O_DEN  = 94638592;   // den fp32 65536
    const size_t O_KSA  = 94704128;   // KsA fp32 65536
    const size_t O_KSP  = 94769664;   // KsP fp32 65536
    const size_t O_KVA  = 94835200;   // KV_A bf16 33.5MB (later: h-strip bf16 67MB)
    const size_t O_KVP  = 161944064;  // KV_P bf16 33554432

    uint16_t* Wqkv  = (uint16_t*)(ws + o_Wqkv);
    uint16_t* Wo    = (uint16_t*)(ws + o_Wo);
    uint16_t* W1    = (uint16_t*)(ws + o_W1);
    uint16_t* W2    = (uint16_t*)(ws + o_W2);
    float*    bqkv  = (float*)(ws + o_bqkv);
    uint16_t* xn    = (uint16_t*)(ws + O_XN);
    uint16_t* attn  = (uint16_t*)(ws + O_XN);   // alias: x_norm dead after QKV GEMM
    uint16_t* QKV   = (uint16_t*)(ws + O_QKV);
    uint16_t* hnorm = (uint16_t*)(ws + O_QKV);  // alias: QKV dead after phase C
    uint16_t* Sg    = (uint16_t*)(ws + O_S);
    float*    den   = (float*)(ws + O_DEN);
    float*    KsA   = (float*)(ws + O_KSA);
    float*    KsP   = (float*)(ws + O_KSP);
    uint16_t* KV_A  = (uint16_t*)(ws + O_KVA);
    uint16_t* hbuf  = (uint16_t*)(ws + O_KVA);  // alias: KV_A dead after prefix
    uint16_t* KV_P  = (uint16_t*)(ws + O_KVP);

    // 1. weight prep
    eel_prep<<<4096, 256, 0, stream>>>(qw, kw, vw, ow, f1w, f2w, qb, kb, vb,
                                       Wqkv, Wo, W1, W2, bqkv);
    // 2. LN1: x -> x_norm (bf16)
    eel_ln<<<16384, 256, 0, stream>>>(x, ln1w, ln1b, xn);
    // 3. QKV projection: [16384,1024] @ [1152,1024]^T -> QKV bf16, elu+1 on Q,K
    eel_gemm<<<dim3(128, 9), 256, 0, stream>>>(xn, 1024, Wqkv, 1024, 1024,
                                               bqkv, nullptr, QKV, nullptr, 1152, 0);
    // 4. phase A1: S, den_intra, Ks per chunk
    eel_attn_s<<<256, 256, 0, stream>>>(QKV, Sg, den, KsA);
    // 5. phase A2: per-chunk KV states (bf16)
    eel_attn_kv<<<2048, 256, 0, stream>>>(QKV, KV_A);
    // 6. phase B1: KV prefix (exclusive), bf16 in/out, fp32 accum
    eel_kv_prefix<<<1024, 256, 0, stream>>>(KV_A, KV_P);
    // 7. phase B2: Ks prefix
    eel_ks_prefix<<<4, 64, 0, stream>>>(KsA, KsP);
    // 8. phase C: attention output -> attn bf16 (aliases x_norm)
    eel_attn_out<<<2048, 256, 0, stream>>>(QKV, Sg, den, KsP, KV_P, attn);
    // 9. O-proj + residual: attn @ Wo^T + ob + x -> d_out (fp32, y1)
    eel_gemm<<<dim3(128, 8), 256, 0, stream>>>(attn, 1024, Wo, 1024, 1024,
                                               ob, x, nullptr, out, 1024, 1);
    // 10. LN2: d_out -> h_norm bf16 (aliases QKV)
    eel_ln<<<16384, 256, 0, stream>>>(out, ln2w, ln2b, hnorm);
    // 11-14. FFN as two N-strips of 2048 over full M=16384:
    //   FFN1 strip: hnorm @ W1[strip]^T -> gelu -> h-strip bf16 [16384,2048]
    //   FFN2 strip: h-strip @ W2[:,strip]^T (+f2b on strip 0) + out -> out
    // FFN2 grid 128x8 = 1024 blocks = 4/CU (was 512 = 2/CU, grid-starved).
    for (int strip = 0; strip < 2; strip++) {
        size_t noff = (size_t)strip * 2048;
        eel_gemm<<<dim3(128, 16), 256, 0, stream>>>(hnorm, 1024, W1 + noff * 1024, 1024, 1024,
                                                    f1b + noff, nullptr, hbuf, nullptr, 2048, 2);
        eel_gemm<<<dim3(128, 8), 256, 0, stream>>>(hbuf, 2048, W2 + noff, 4096, 2048,
                                                   strip == 0 ? f2bs : nullptr, out, nullptr,
                                                   out, 1024, 1);
    }
}

// Round 4
// 816.527 us; speedup vs baseline: 1.1079x; 1.1079x over previous
//
#include <hip/hip_runtime.h>
#include <hip/hip_bf16.h>
#include <cstdint>
#include <cstddef>

// ---------------------------------------------------------------------------
// EfficientEquilibriumLayer: LN1 -> QKV(elu+1 on Q,K) -> chunked causal linear
// attention -> O-proj + residual -> LN2 -> GELU FFN + residual.
// B=4, N=4096, D=1024, F=64. All GEMMs bf16 MFMA (16x16x32), fp32 accum.
// R1: XOR-swizzled LDS (bank conflicts 2.5e7 -> 0), tanh-GELU epilogue.
// R2: FFN as N-strips over full M (FFN2 1024 blocks, was 512 grid-starved).
// R3 (this): L2-locality block swizzle in eel_gemm — y (weight tile) fastest
//     within groups of 8 x-panels, so the 2-4MB weight strip stays L2-hot and
//     A streams once (FFN1 strip FETCH was 128MB vs 38MB ideal; staging loads
//     were HBM-latency ~900cyc instead of L2 ~200cyc in the vmcnt(0) drain).
// ---------------------------------------------------------------------------

typedef __attribute__((ext_vector_type(8))) short short8;
typedef __attribute__((ext_vector_type(4))) short short4v;
typedef __attribute__((ext_vector_type(4))) float floatx4;
typedef __attribute__((ext_vector_type(4))) unsigned short ushort4v;

#define DEV static __device__ __forceinline__

DEV float b2f(unsigned short u) {
    union { unsigned int i; float f; } v; v.i = ((unsigned int)u) << 16; return v.f;
}
DEV unsigned short f2b(float f) {
    union { float f; unsigned int i; } v; v.f = f;
    unsigned int i = v.i;
    unsigned int r = (i + 0x7FFFu + ((i >> 16) & 1u)) >> 16;
    return (unsigned short)r;
}

DEV void gl_lds16(const void* g, void* l) {
    __builtin_amdgcn_global_load_lds((const __attribute__((address_space(1))) void*)g,
                                     (__attribute__((address_space(3))) void*)l, 16, 0, 0);
}

// ---------------------------------------------------------------------------
// Weight prep: fp32 -> bf16, concat q/k/v weights into Wqkv [1152,1024],
// concat biases into bqkv [1152].
// ---------------------------------------------------------------------------
__global__ void eel_prep(const float* __restrict__ qw, const float* __restrict__ kw,
                         const float* __restrict__ vw, const float* __restrict__ ow,
                         const float* __restrict__ f1w, const float* __restrict__ f2w,
                         const float* __restrict__ qb, const float* __restrict__ kb,
                         const float* __restrict__ vb,
                         uint16_t* __restrict__ Wqkv, uint16_t* __restrict__ Wo,
                         uint16_t* __restrict__ W1, uint16_t* __restrict__ W2,
                         float* __restrict__ bqkv)
{
    size_t i = (size_t)blockIdx.x * 256 + threadIdx.x;
    size_t stride = (size_t)gridDim.x * 256;
    for (size_t t = i; t < 1152u * 1024u; t += stride) {
        int r = (int)(t >> 10);
        float v = (r < 64) ? qw[t] : (r < 128) ? kw[t - 65536] : vw[t - 131072];
        Wqkv[t] = f2b(v);
    }
    for (size_t t = i; t < 1048576u; t += stride) Wo[t] = f2b(ow[t]);
    for (size_t t = i; t < 4194304u; t += stride) { W1[t] = f2b(f1w[t]); W2[t] = f2b(f2w[t]); }
    if (i < 1152) bqkv[i] = (i < 64) ? qb[i] : (i < 128) ? kb[i - 64] : vb[i - 128];
}

// ---------------------------------------------------------------------------
// LayerNorm: one block per row (D=1024), fp32 in -> bf16 out.
// ---------------------------------------------------------------------------
__global__ __launch_bounds__(256) void eel_ln(const float* __restrict__ x,
                                              const float* __restrict__ w,
                                              const float* __restrict__ b,
                                              uint16_t* __restrict__ out)
{
    int row = blockIdx.x, tid = threadIdx.x;
    float4 xv = ((const float4*)(x + (size_t)row * 1024))[tid];
    float s  = xv.x + xv.y + xv.z + xv.w;
    float s2 = xv.x*xv.x + xv.y*xv.y + xv.z*xv.z + xv.w*xv.w;
#pragma unroll
    for (int off = 32; off > 0; off >>= 1) {
        s  += __shfl_down(s, off);
        s2 += __shfl_down(s2, off);
    }
    __shared__ float ps[8];
    int wv = tid >> 6;
    if ((tid & 63) == 0) { ps[wv] = s; ps[4 + wv] = s2; }
    __syncthreads();
    float mu  = (ps[0] + ps[1] + ps[2] + ps[3]) * (1.0f / 1024.0f);
    float var = (ps[4] + ps[5] + ps[6] + ps[7]) * (1.0f / 1024.0f) - mu * mu;
    float rs = rsqrtf(var + 1e-5f);
    float4 wv4 = ((const float4*)w)[tid];
    float4 bv4 = ((const float4*)b)[tid];
    ushort4v o;
    o.x = f2b((xv.x - mu) * rs * wv4.x + bv4.x);
    o.y = f2b((xv.y - mu) * rs * wv4.y + bv4.y);
    o.z = f2b((xv.z - mu) * rs * wv4.z + bv4.z);
    o.w = f2b((xv.w - mu) * rs * wv4.w + bv4.w);
    *(ushort4v*)(out + (size_t)row * 1024 + tid * 4) = o;
}

// ---------------------------------------------------------------------------
// GEMM: C[M,N] = A[M,K] @ B[N,K]^T (+epilogue). bf16 inputs, fp32 accum.
// 128x128 tile, BK=64, 4 waves, 16x16x32 MFMA, global_load_lds staging,
// XOR-swizzled LDS k-segments (conflict-free ds_read_b128).
// Block swizzle: y fastest within groups of 8 x-panels (weight tiles L2-hot).
// Requires gridDim.x % 8 == 0 (all call sites use 64/128).
// mode 0: out bf16 = acc+bias, cols<128 get elu(x)+1         (QKV proj)
// mode 1: out fp32 = acc+[bias]+res                          (O-proj / FFN2)
// mode 2: out bf16 = gelu_tanh(acc+bias)                     (FFN1)
// bias may be nullptr (treated as 0).
// ---------------------------------------------------------------------------
#define BM 128
#define BN 128
#define BKK 64

__global__ __launch_bounds__(256, 2) void eel_gemm(
    const uint16_t* __restrict__ A, int lda,
    const uint16_t* __restrict__ Bm, int ldb,
    int K,
    const float* __restrict__ bias,
    const float* __restrict__ res,
    uint16_t* __restrict__ outb,
    float* __restrict__ outf,
    int ldc, int mode)
{
    __shared__ uint16_t As[BM * BKK];
    __shared__ uint16_t Bs[BN * BKK];
    int tid = threadIdx.x;
    int lane = tid & 63, w = tid >> 6;
    // L2-locality swizzle: linear id -> (bx, by) with by fastest in 8-wide
    // x-groups, so co-resident blocks share the weight (B) strip.
    int lin  = blockIdx.y * gridDim.x + blockIdx.x;
    int span = 8 * gridDim.y;
    int g = lin / span, r = lin % span;
    int bx = g * 8 + (r & 7);
    int by = r >> 3;
    int m0 = bx * BM, n0 = by * BN;
    int wr = (w >> 1) * 64, wc = (w & 1) * 64;
    int quad = lane >> 4, l16 = lane & 15;
    floatx4 acc[4][4] = {};

    int nkb = K / BKK;
    for (int kb = 0; kb < nkb; ++kb) {
        int k0 = kb * BKK;
#pragma unroll
        for (int it = 0; it < 4; ++it) {
            int seg = it * 256 + tid;
            int row = seg >> 3, sub = seg & 7;
            int gs = sub ^ (row & 7);   // source k-segment for swizzled slot
            gl_lds16(A + (size_t)(m0 + row) * lda + k0 + gs * 8, (char*)As + seg * 16);
            gl_lds16(Bm + (size_t)(n0 + row) * ldb + k0 + gs * 8, (char*)Bs + seg * 16);
        }
        __syncthreads();
#pragma unroll
        for (int ks = 0; ks < 2; ++ks) {
            short8 a[4], b[4];
#pragma unroll
            for (int i = 0; i < 4; i++) {
                int mrow = wr + i * 16 + l16;
                int sa = (ks * 4 + quad) ^ (mrow & 7);
                a[i] = *(const short8*)((const char*)As + mrow * (BKK * 2) + sa * 16);
                int nrow = wc + i * 16 + l16;
                int sb = (ks * 4 + quad) ^ (nrow & 7);
                b[i] = *(const short8*)((const char*)Bs + nrow * (BKK * 2) + sb * 16);
            }
#pragma unroll
            for (int i = 0; i < 4; i++)
#pragma unroll
                for (int j = 0; j < 4; j++)
                    acc[i][j] = __builtin_amdgcn_mfma_f32_16x16x32_bf16(a[i], b[j], acc[i][j], 0, 0, 0);
        }
        __syncthreads();
    }

#pragma unroll
    for (int j = 0; j < 4; j++) {
        int col = n0 + wc + j * 16 + l16;
        float bv = bias ? bias[col] : 0.0f;
#pragma unroll
        for (int i = 0; i < 4; i++) {
#pragma unroll
            for (int r2 = 0; r2 < 4; r2++) {
                int row = m0 + wr + i * 16 + quad * 4 + r2;
                float v = acc[i][j][r2] + bv;
                size_t off = (size_t)row * ldc + col;
                if (mode == 0) {
                    if (col < 128) v = (v > 0.f) ? v + 1.f : __expf(v);
                    outb[off] = f2b(v);
                } else if (mode == 1) {
                    outf[off] = v + res[off];
                } else {
                    // gelu tanh-approx; tanh(u) = 1 - 2/(exp(2u)+1), inf-safe
                    float u = 0.7978845608028654f * v * (1.0f + 0.044715f * v * v);
                    float e = __expf(2.0f * u);
                    float t = 1.0f - 2.0f / (e + 1.0f);
                    v = 0.5f * v * (1.0f + t);
                    outb[off] = f2b(v);
                }
            }
        }
    }
}

// ---------------------------------------------------------------------------
// Attention phase A1: per chunk (64 tokens) compute S = causal(Q K^T) (bf16),
// den_intra[n] = rowsum(S), Ks_c[f] = colsum(K). One block per chunk.
// QKV layout: [16384][1152] bf16, Q at col 0, K at 64, V at 128.
// ---------------------------------------------------------------------------
__global__ __launch_bounds__(256) void eel_attn_s(
    const uint16_t* __restrict__ QKV,
    uint16_t* __restrict__ Sg,      // [16384][64]
    float* __restrict__ den,        // [16384]
    float* __restrict__ KsA)        // [256][64]
{
    int chunk = blockIdx.x, tid = threadIdx.x;
    int tok0 = chunk * 64;
    __shared__ uint16_t Q[64 * 64];
    __shared__ uint16_t Kc[64 * 64];
    __shared__ float denp[64][4];
    {
        int nloc = tid >> 2, seg = tid & 3;
        const uint16_t* src = QKV + (size_t)(tok0 + nloc) * 1152 + seg * 16;
        *(short8*)(Q + nloc * 64 + seg * 16)     = *(const short8*)(src);
        *(short8*)(Q + nloc * 64 + seg * 16 + 8) = *(const short8*)(src + 8);
        src += 64;
        *(short8*)(Kc + nloc * 64 + seg * 16)     = *(const short8*)(src);
        *(short8*)(Kc + nloc * 64 + seg * 16 + 8) = *(const short8*)(src + 8);
    }
    __syncthreads();
    if (tid < 64) {
        float s = 0.f;
        for (int m = 0; m < 64; m++) s += b2f(Kc[m * 64 + tid]);
        KsA[chunk * 64 + tid] = s;
    }
    int n = tid >> 2, mg = tid & 3;
    float dsum = 0.f;
    for (int mi = 0; mi < 16; mi++) {
        int m = mg * 16 + mi;
        size_t soff = (size_t)(tok0 + n) * 64 + m;
        if (m <= n) {
            float s = 0.f;
#pragma unroll
            for (int f = 0; f < 64; f += 8) {
                short8 q8 = *(const short8*)(Q + n * 64 + f);
                short8 k8 = *(const short8*)(Kc + m * 64 + f);
#pragma unroll
                for (int j = 0; j < 8; j++)
                    s += b2f((unsigned short)q8[j]) * b2f((unsigned short)k8[j]);
            }
            dsum += s;
            Sg[soff] = f2b(s);
        } else {
            Sg[soff] = 0;
        }
    }
    denp[n][mg] = dsum;
    __syncthreads();
    if (tid < 64)
        den[tok0 + tid] = denp[tid][0] + denp[tid][1] + denp[tid][2] + denp[tid][3];
}

// ---------------------------------------------------------------------------
// Attention phase A2: per (chunk, d-panel of 128) compute KV_c[f, d] = K^T V.
// Output bf16 [256 chunks][64 f][1024 d].
// ---------------------------------------------------------------------------
__global__ __launch_bounds__(256) void eel_attn_kv(
    const uint16_t* __restrict__ QKV,
    uint16_t* __restrict__ KV_A)
{
    int bi = blockIdx.x;
    int chunk = bi >> 3, p = bi & 7;
    int tid = threadIdx.x;
    int tok0 = chunk * 64;
    __shared__ uint16_t Kc[64 * 64];
    __shared__ uint16_t Vp[64 * 128];
    {
        int r = tid >> 2, sg = tid & 3;
        const uint16_t* src = QKV + (size_t)(tok0 + r) * 1152 + 64 + sg * 16;
        *(short8*)(Kc + r * 64 + sg * 16)     = *(const short8*)(src);
        *(short8*)(Kc + r * 64 + sg * 16 + 8) = *(const short8*)(src + 8);
    }
#pragma unroll
    for (int it = 0; it < 2; it++) {
        int s = it * 256 + tid;
        int r = s >> 3, sub = s & 7;
        const uint16_t* src = QKV + (size_t)(tok0 + r) * 1152 + 128 + p * 128 + sub * 16;
        *(short8*)(Vp + r * 128 + sub * 16)     = *(const short8*)(src);
        *(short8*)(Vp + r * 128 + sub * 16 + 8) = *(const short8*)(src + 8);
    }
    __syncthreads();
    int f0 = (tid >> 5) * 8, d0 = (tid & 31) * 4;
    float acc[8][4] = {};
#pragma unroll 2
    for (int m = 0; m < 64; m++) {
        short8 k8 = *(const short8*)(Kc + m * 64 + f0);
        short4v v4 = *(const short4v*)(Vp + m * 128 + d0);
        float v0 = b2f((unsigned short)v4[0]), v1 = b2f((unsigned short)v4[1]);
        float v2 = b2f((unsigned short)v4[2]), v3 = b2f((unsigned short)v4[3]);
#pragma unroll
        for (int i = 0; i < 8; i++) {
            float kk = b2f((unsigned short)k8[i]);
            acc[i][0] += kk * v0; acc[i][1] += kk * v1;
            acc[i][2] += kk * v2; acc[i][3] += kk * v3;
        }
    }
#pragma unroll
    for (int i = 0; i < 8; i++) {
        ushort4v st;
        st.x = f2b(acc[i][0]); st.y = f2b(acc[i][1]);
        st.z = f2b(acc[i][2]); st.w = f2b(acc[i][3]);
        *(ushort4v*)(KV_A + ((size_t)chunk * 64 + f0 + i) * 1024 + p * 128 + d0) = st;
    }
}

// ---------------------------------------------------------------------------
// Phase B1: exclusive prefix over 64 chunks per batch of KV states (bf16 in,
// fp32 accum, bf16 out). Grid: 1024 blocks (b*256 + f*4 + dseg), 256 threads.
// ---------------------------------------------------------------------------
__global__ __launch_bounds__(256) void eel_kv_prefix(
    const uint16_t* __restrict__ KV_A, uint16_t* __restrict__ KV_P)
{
    int bi = blockIdx.x;
    int b = bi >> 8, rem = bi & 255;
    int f = rem >> 2;
    int d = (rem & 3) * 256 + threadIdx.x;
    float acc = 0.f;
    for (int cc = 0; cc < 64; cc++) {
        size_t idx = (((size_t)(b * 64 + cc)) * 64 + f) * 1024 + d;
        KV_P[idx] = f2b(acc);
        acc += b2f(KV_A[idx]);
    }
}

// Phase B2: exclusive prefix of Ks over chunks. Grid 4 x 64 threads.
__global__ void eel_ks_prefix(const float* __restrict__ KsA, float* __restrict__ KsP)
{
    int b = blockIdx.x, f = threadIdx.x;
    float acc = 0.f;
    for (int cc = 0; cc < 64; cc++) {
        int idx = (b * 64 + cc) * 64 + f;
        KsP[idx] = acc;
        acc += KsA[idx];
    }
}

// ---------------------------------------------------------------------------
// Phase C: per (chunk, d-panel) attn[n,d] = (Q·KV_prev + S·V) / den_full.
// ---------------------------------------------------------------------------
__global__ __launch_bounds__(256) void eel_attn_out(
    const uint16_t* __restrict__ QKV,
    const uint16_t* __restrict__ Sg,
    const float* __restrict__ den,
    const float* __restrict__ KsP,
    const uint16_t* __restrict__ KV_P,
    uint16_t* __restrict__ attn)    // [16384][1024] bf16
{
    int bi = blockIdx.x;
    int chunk = bi >> 3, p = bi & 7;
    int tid = threadIdx.x;
    int tok0 = chunk * 64;
    __shared__ uint16_t Qt[64 * 64];    // [f][n]
    __shared__ uint16_t St[64 * 64];    // [m][n]
    __shared__ uint16_t Vp[64 * 128];   // [m][d]
    __shared__ uint16_t KVp[64 * 128];  // [f][d]
    __shared__ float dfull[64];
    {
        int n = tid >> 2, fs = (tid & 3) * 16;
        const uint16_t* qsrc = QKV + (size_t)(tok0 + n) * 1152 + fs;
        short8 a0 = *(const short8*)(qsrc);
        short8 a1 = *(const short8*)(qsrc + 8);
        const uint16_t* ssrc = Sg + (size_t)(tok0 + n) * 64 + fs;
        short8 s0 = *(const short8*)(ssrc);
        short8 s1 = *(const short8*)(ssrc + 8);
#pragma unroll
        for (int j = 0; j < 8; j++) {
            Qt[(fs + j) * 64 + n]     = (unsigned short)a0[j];
            Qt[(fs + 8 + j) * 64 + n] = (unsigned short)a1[j];
            St[(fs + j) * 64 + n]     = (unsigned short)s0[j];
            St[(fs + 8 + j) * 64 + n] = (unsigned short)s1[j];
        }
    }
#pragma unroll
    for (int it = 0; it < 2; it++) {
        int s = it * 256 + tid;
        int r = s >> 3, sub = s & 7;
        const uint16_t* vsrc = QKV + (size_t)(tok0 + r) * 1152 + 128 + p * 128 + sub * 16;
        *(short8*)(Vp + r * 128 + sub * 16)     = *(const short8*)(vsrc);
        *(short8*)(Vp + r * 128 + sub * 16 + 8) = *(const short8*)(vsrc + 8);
        const uint16_t* kvsrc = KV_P + ((size_t)(chunk * 64 + r)) * 1024 + p * 128 + sub * 16;
        *(short8*)(KVp + r * 128 + sub * 16)     = *(const short8*)(kvsrc);
        *(short8*)(KVp + r * 128 + sub * 16 + 8) = *(const short8*)(kvsrc + 8);
    }
    __syncthreads();
    if (tid < 64) {
        float s = 0.f;
        for (int f = 0; f < 64; f++)
            s += b2f(Qt[f * 64 + tid]) * KsP[chunk * 64 + f];
        dfull[tid] = s + den[tok0 + tid] + 1e-6f;
    }
    __syncthreads();
    int n0 = (tid >> 5) * 8, d0 = (tid & 31) * 4;
    float acc[8][4] = {};
#pragma unroll 2
    for (int f = 0; f < 64; f++) {
        short8 q8 = *(const short8*)(Qt + f * 64 + n0);
        short4v kv4 = *(const short4v*)(KVp + f * 128 + d0);
        float v0 = b2f((unsigned short)kv4[0]), v1 = b2f((unsigned short)kv4[1]);
        float v2 = b2f((unsigned short)kv4[2]), v3 = b2f((unsigned short)kv4[3]);
#pragma unroll
        for (int i = 0; i < 8; i++) {
            float q = b2f((unsigned short)q8[i]);
            acc[i][0] += q * v0; acc[i][1] += q * v1;
            acc[i][2] += q * v2; acc[i][3] += q * v3;
        }
    }
#pragma unroll 2
    for (int m = 0; m < 64; m++) {
        short8 s8 = *(const short8*)(St + m * 64 + n0);
        short4v v4 = *(const short4v*)(Vp + m * 128 + d0);
        float v0 = b2f((unsigned short)v4[0]), v1 = b2f((unsigned short)v4[1]);
        float v2 = b2f((unsigned short)v4[2]), v3 = b2f((unsigned short)v4[3]);
#pragma unroll
        for (int i = 0; i < 8; i++) {
            float q = b2f((unsigned short)s8[i]);
            acc[i][0] += q * v0; acc[i][1] += q * v1;
            acc[i][2] += q * v2; acc[i][3] += q * v3;
        }
    }
#pragma unroll
    for (int i = 0; i < 8; i++) {
        int n = n0 + i;
        float rinv = 1.0f / dfull[n];
        ushort4v st;
        st.x = f2b(acc[i][0] * rinv);
        st.y = f2b(acc[i][1] * rinv);
        st.z = f2b(acc[i][2] * rinv);
        st.w = f2b(acc[i][3] * rinv);
        *(ushort4v*)(attn + (size_t)(tok0 + n) * 1024 + p * 128 + d0) = st;
    }
}

// ---------------------------------------------------------------------------
// Host launcher
// ---------------------------------------------------------------------------
extern "C" void kernel_launch(void* const* d_in, const int* in_sizes, int n_in,
                              void* d_out, int out_size, void* d_ws, size_t ws_size,
                              hipStream_t stream)
{
    (void)in_sizes; (void)n_in; (void)out_size; (void)ws_size;
    const float* x     = (const float*)d_in[0];
    const float* ln1w  = (const float*)d_in[1];
    const float* ln1b  = (const float*)d_in[2];
    const float* qw    = (const float*)d_in[3];
    const float* qb    = (const float*)d_in[4];
    const float* kw    = (const float*)d_in[5];
    const float* kb    = (const float*)d_in[6];
    const float* vw    = (const float*)d_in[7];
    const float* vb    = (const float*)d_in[8];
    const float* ow    = (const float*)d_in[9];
    const float* ob    = (const float*)d_in[10];
    const float* ln2w  = (const float*)d_in[11];
    const float* ln2b  = (const float*)d_in[12];
    const float* f1w   = (const float*)d_in[13];
    const float* f1b   = (const float*)d_in[14];
    const float* f2w   = (const float*)d_in[15];
    const float* f2bs  = (const float*)d_in[16];
    float* out = (float*)d_out;
    char* ws = (char*)d_ws;

    // workspace layout (bytes)
    const size_t o_Wqkv = 0;                              // 1152*1024*2
    const size_t o_Wo   = o_Wqkv + 2359296;               // 1024*1024*2
    const size_t o_W1   = o_Wo   + 2097152;               // 4096*1024*2
    const size_t o_W2   = o_W1   + 8388608;               // 1024*4096*2
    const size_t o_bqkv = o_W2   + 8388608;               // 1152*4
    const size_t O_XN   = 21238272;   // x_norm bf16 33554432 (later: attn)
    const size_t O_QKV  = 54792704;   // QKV bf16 37748736    (later: h_norm)
    const size_t O_S    = 92541440;   // S bf16 2097152
    const size_t O_DEN  = 94638592;   // den fp32 65536
    const size_t O_KSA  = 94704128;   // KsA fp32 65536
    const size_t O_KSP  = 94769664;   // KsP fp32 65536
    const size_t O_KVA  = 94835200;   // KV_A bf16 33.5MB (later: h-strip bf16 67MB)
    const size_t O_KVP  = 161944064;  // KV_P bf16 33554432

    uint16_t* Wqkv  = (uint16_t*)(ws + o_Wqkv);
    uint16_t* Wo    = (uint16_t*)(ws + o_Wo);
    uint16_t* W1    = (uint16_t*)(ws + o_W1);
    uint16_t* W2    = (uint16_t*)(ws + o_W2);
    float*    bqkv  = (float*)(ws + o_bqkv);
    uint16_t* xn    = (uint16_t*)(ws + O_XN);
    uint16_t* attn  = (uint16_t*)(ws + O_XN);   // alias: x_norm dead after QKV GEMM
    uint16_t* QKV   = (uint16_t*)(ws + O_QKV);
    uint16_t* hnorm = (uint16_t*)(ws + O_QKV);  // alias: QKV dead after phase C
    uint16_t* Sg    = (uint16_t*)(ws + O_S);
    float*    den   = (float*)(ws + O_DEN);
    float*    KsA   = (float*)(ws + O_KSA);
    float*    KsP   = (float*)(ws + O_KSP);
    uint16_t* KV_A  = (uint16_t*)(ws + O_KVA);
    uint16_t* hbuf  = (uint16_t*)(ws + O_KVA);  // alias: KV_A dead after prefix
    uint16_t* KV_P  = (uint16_t*)(ws + O_KVP);

    // 1. weight prep
    eel_prep<<<4096, 256, 0, stream>>>(qw, kw, vw, ow, f1w, f2w, qb, kb, vb,
                                       Wqkv, Wo, W1, W2, bqkv);
    // 2. LN1: x -> x_norm (bf16)
    eel_ln<<<16384, 256, 0, stream>>>(x, ln1w, ln1b, xn);
    // 3. QKV projection: [16384,1024] @ [1152,1024]^T -> QKV bf16, elu+1 on Q,K
    eel_gemm<<<dim3(128, 9), 256, 0, stream>>>(xn, 1024, Wqkv, 1024, 1024,
                                               bqkv, nullptr, QKV, nullptr, 1152, 0);
    // 4. phase A1: S, den_intra, Ks per chunk
    eel_attn_s<<<256, 256, 0, stream>>>(QKV, Sg, den, KsA);
    // 5. phase A2: per-chunk KV states (bf16)
    eel_attn_kv<<<2048, 256, 0, stream>>>(QKV, KV_A);
    // 6. phase B1: KV prefix (exclusive), bf16 in/out, fp32 accum
    eel_kv_prefix<<<1024, 256, 0, stream>>>(KV_A, KV_P);
    // 7. phase B2: Ks prefix
    eel_ks_prefix<<<4, 64, 0, stream>>>(KsA, KsP);
    // 8. phase C: attention output -> attn bf16 (aliases x_norm)
    eel_attn_out<<<2048, 256, 0, stream>>>(QKV, Sg, den, KsP, KV_P, attn);
    // 9. O-proj + residual: attn @ Wo^T + ob + x -> d_out (fp32, y1)
    eel_gemm<<<dim3(128, 8), 256, 0, stream>>>(attn, 1024, Wo, 1024, 1024,
                                               ob, x, nullptr, out, 1024, 1);
    // 10. LN2: d_out -> h_norm bf16 (aliases QKV)
    eel_ln<<<16384, 256, 0, stream>>>(out, ln2w, ln2b, hnorm);
    // 11-14. FFN as two N-strips of 2048 over full M=16384:
    //   FFN1 strip: hnorm @ W1[strip]^T -> gelu -> h-strip bf16 [16384,2048]
    //   FFN2 strip: h-strip @ W2[:,strip]^T (+f2b on strip 0) + out -> out
    for (int strip = 0; strip < 2; strip++) {
        size_t noff = (size_t)strip * 2048;
        eel_gemm<<<dim3(128, 16), 256, 0, stream>>>(hnorm, 1024, W1 + noff * 1024, 1024, 1024,
                                                    f1b + noff, nullptr, hbuf, nullptr, 2048, 2);
        eel_gemm<<<dim3(128, 8), 256, 0, stream>>>(hbuf, 2048, W2 + noff, 4096, 2048,
                                                   strip == 0 ? f2bs : nullptr, out, nullptr,
                                                   out, 1024, 1);
    }
}